// Round 13
// baseline (59.011 us; speedup 1.0000x reference)
//
#include <hip/hip_runtime.h>

// AttentionBlock: B=16, C=256, H=W=32, NH=4, GROUPS=8
#define NB 16
#define NC 256
#define NS 1024   // H*W
#define NNH 4
#define ND 64     // C/NH
#define GN_EPS 1e-5f

typedef __attribute__((ext_vector_type(8))) short short8;   // 8 bf16 (4 VGPRs)
typedef __attribute__((ext_vector_type(4))) float f32x4;    // MFMA C/D

static __device__ __forceinline__ ushort f2bf(float x) {
  union { float f; unsigned u; } c; c.f = x;
  unsigned r = (c.u + 0x7fffu + ((c.u >> 16) & 1u)) >> 16;  // RNE
  return (ushort)r;
}
static __device__ __forceinline__ unsigned cvt_pk_bf16(float lo, float hi) {
  unsigned r;
  asm("v_cvt_pk_bf16_f32 %0, %1, %2" : "=v"(r) : "v"(lo), "v"(hi));
  return r;  // low16 = bf16(lo), high16 = bf16(hi)
}

// ---------------------------------------------------------------------------
// Kernel 1: blocks 0..1023: x [b][c][s] fp32 -> xT [b][s][c] RAW bf16 (LDS
// transpose) + per-(b,g,s-tile) stat partials.  Blocks 1024..1279: weight
// fp32->bf16 convert (qkv_w then proj_w).
// ---------------------------------------------------------------------------
__global__ __launch_bounds__(256) void gnstatT_wconv_kernel(
    const float* __restrict__ x, ushort* __restrict__ xT,
    float2* __restrict__ partials, const float* __restrict__ qw,
    const float* __restrict__ pw, ushort* __restrict__ wbf) {
  const int bid = blockIdx.x;
  const int t = threadIdx.x;
  if (bid >= 1024) {  // ---- weight convert: 65536 float4s over 256 blocks ----
    const int i = (bid - 1024) * 256 + t;
    const float4 v = (i < 49152) ? *(const float4*)(qw + (size_t)i * 4)
                                 : *(const float4*)(pw + (size_t)(i - 49152) * 4);
    ushort4 u;
    u.x = f2bf(v.x); u.y = f2bf(v.y); u.z = f2bf(v.z); u.w = f2bf(v.w);
    *(ushort4*)(wbf + (size_t)i * 4) = u;
    return;
  }
  const int bg = bid >> 3, st = bid & 7;
  const int b = bg >> 3, gg = bg & 7;

  __shared__ ushort tile[128][36];  // 72B rows
  __shared__ float rs1[4], rs2[4];
  const int s4 = (t & 31) * 4;
  float s1 = 0.f, s2 = 0.f;
  #pragma unroll
  for (int i = 0; i < 4; ++i) {
    const int c = (t >> 5) + 8 * i;
    const int cg = gg * 32 + c;
    const float4 v = *(const float4*)(x + ((size_t)(b * NC + cg)) * NS +
                                      st * 128 + s4);
    s1 += v.x + v.y + v.z + v.w;
    s2 += v.x * v.x + v.y * v.y + v.z * v.z + v.w * v.w;
    tile[s4 + 0][c] = f2bf(v.x);
    tile[s4 + 1][c] = f2bf(v.y);
    tile[s4 + 2][c] = f2bf(v.z);
    tile[s4 + 3][c] = f2bf(v.w);
  }
  #pragma unroll
  for (int o = 32; o > 0; o >>= 1) {
    s1 += __shfl_down(s1, o, 64);
    s2 += __shfl_down(s2, o, 64);
  }
  if ((t & 63) == 0) { rs1[t >> 6] = s1; rs2[t >> 6] = s2; }
  __syncthreads();   // orders tile writes AND rs writes
  if (t == 0)
    partials[bid] = make_float2(rs1[0] + rs1[1] + rs1[2] + rs1[3],
                                rs2[0] + rs2[1] + rs2[2] + rs2[3]);
  #pragma unroll
  for (int i = 0; i < 4; ++i) {
    const int idx = t + 256 * i;         // 128 rows x 8 chunks
    const int sr = idx >> 3, ch4 = (idx & 7) * 4;
    const ushort4 u = *(const ushort4*)&tile[sr][ch4];
    *(ushort4*)(xT + ((size_t)(b * NS + st * 128 + sr)) * NC + gg * 32 + ch4) = u;
  }
}

// ---------------------------------------------------------------------------
// Kernel 2/4: bf16 MFMA GEMM, XCD-chunked 1D grid, T14 async-stage K-loop.
// EPI=0: raw xT + GN affine cooked at ds_write time; qT/kT epilogue goes
//        through a per-wave LDS transpose tile -> fully coalesced 16B stores.
// EPI=1: proj epilogue fp32 + bias + residual (already coalesced).
// ---------------------------------------------------------------------------
template <int EPI, int YDIM>
__global__ __launch_bounds__(256) void mfma_gemm_kernel(
    const ushort* __restrict__ Wbf, const float* __restrict__ bias,
    const ushort* __restrict__ DATA, const float* __restrict__ X,
    const float* __restrict__ nw, const float* __restrict__ nb,
    const float2* __restrict__ partials,
    ushort* __restrict__ qT, ushort* __restrict__ kT, ushort* __restrict__ vN,
    float* __restrict__ OUT) {
  __shared__ char smem[32768];
  __shared__ float2 sm_wb[256];  // per-channel {wgt, bia} (EPI=0)
  __shared__ float2 sm_g[8];
  char* T1 = smem;          // W-tile   [128 o][64 c] bf16, swizzled 128B rows
  char* T2 = smem + 16384;  // data-tile[128 s][64 c] bf16, swizzled
  const int nwg = 8 * YDIM * NB;
  const int o_id = blockIdx.x;
  const int wg = (o_id & 7) * (nwg >> 3) + (o_id >> 3);
  const int b = wg / (8 * YDIM);
  const int o0 = ((wg >> 3) % YDIM) * 128, s0 = (wg & 7) * 128;
  const int t = threadIdx.x, w = t >> 6, l = t & 63;
  const int g = l >> 4, li = l & 15;
  const ushort* wrow = Wbf + (size_t)o0 * NC;
  const ushort* drow = DATA + ((size_t)b * NS + s0) * NC;

  const int oh = (w >> 1) * 64, sh = (w & 1) * 64;  // wave quadrant
  const int srow = t >> 3, sce = (t & 7) * 8;       // staging row/col (elems)
  // rows srow+32*i share (row&7) == (srow&7) -> same swizzle term for all i
  const int sds = srow * 128 + (((t & 7) * 16) ^ ((srow & 7) << 4));

  short8 r1[4], r2[4];   // staged regs: rows srow+32*i of current K-tile
  #pragma unroll
  for (int i = 0; i < 4; ++i) {
    r1[i] = *(const short8*)(wrow + (size_t)(srow + 32 * i) * NC + sce);
    r2[i] = *(const short8*)(drow + (size_t)(srow + 32 * i) * NC + sce);
  }

  if (EPI == 0) {  // build per-channel GN affine table in LDS
    if (t < 8) {
      float s1 = 0.f, s2 = 0.f;
      #pragma unroll
      for (int j = 0; j < 8; ++j) {
        const float2 p = partials[(b * 8 + t) * 8 + j];
        s1 += p.x; s2 += p.y;
      }
      const float mean = s1 * (1.f / 32768.f);
      const float var = s2 * (1.f / 32768.f) - mean * mean;
      sm_g[t] = make_float2(mean, rsqrtf(var + GN_EPS));
    }
    __syncthreads();
    const float2 ms = sm_g[t >> 5];
    const float wgt = nw[t] * ms.y;
    sm_wb[t] = make_float2(wgt, nb[t] - ms.x * wgt);
    // (first K-loop barrier orders sm_wb writes before first cook read)
  }

  f32x4 acc[4][4];
  #pragma unroll
  for (int i = 0; i < 4; ++i)
    #pragma unroll
    for (int j = 0; j < 4; ++j) acc[i][j] = (f32x4){0.f, 0.f, 0.f, 0.f};

  for (int k0 = 0; k0 < NC; k0 += 64) {
    __syncthreads();   // previous iteration's LDS reads complete
    #pragma unroll
    for (int i = 0; i < 4; ++i)
      *(short8*)(T1 + sds + i * 4096) = r1[i];
    if (EPI == 0) {  // cook: y = bf16(x)*wgt + bia, per channel k0+sce+j
      float2 wb[8];
      #pragma unroll
      for (int j = 0; j < 8; ++j) wb[j] = sm_wb[k0 + sce + j];
      #pragma unroll
      for (int i = 0; i < 4; ++i) {
        union { short8 s; unsigned u[4]; } a, o;
        a.s = r2[i];
        #pragma unroll
        for (int j = 0; j < 4; ++j) {
          const float lo = __uint_as_float(a.u[j] << 16);
          const float hi = __uint_as_float(a.u[j] & 0xffff0000u);
          o.u[j] = cvt_pk_bf16(fmaf(lo, wb[2 * j].x, wb[2 * j].y),
                               fmaf(hi, wb[2 * j + 1].x, wb[2 * j + 1].y));
        }
        *(short8*)(T2 + sds + i * 4096) = o.s;
      }
    } else {
      #pragma unroll
      for (int i = 0; i < 4; ++i)
        *(short8*)(T2 + sds + i * 4096) = r2[i];
    }
    __syncthreads();
    if (k0 + 64 < NC) {  // issue next tile's loads; hide under MFMA
      #pragma unroll
      for (int i = 0; i < 4; ++i) {
        r1[i] = *(const short8*)(wrow + (size_t)(srow + 32 * i) * NC + k0 + 64 + sce);
        r2[i] = *(const short8*)(drow + (size_t)(srow + 32 * i) * NC + k0 + 64 + sce);
      }
    }
    __builtin_amdgcn_s_setprio(1);
    #pragma unroll
    for (int kk = 0; kk < 2; ++kk) {
      short8 af[4], bfr[4];
      #pragma unroll
      for (int ms = 0; ms < 4; ++ms) {
        const int row = oh + ms * 16 + li;
        af[ms] = *(const short8*)(T1 + row * 128 +
                                  ((kk * 64 + g * 16) ^ ((row & 7) << 4)));
      }
      #pragma unroll
      for (int ns = 0; ns < 4; ++ns) {
        const int row = sh + ns * 16 + li;
        bfr[ns] = *(const short8*)(T2 + row * 128 +
                                   ((kk * 64 + g * 16) ^ ((row & 7) << 4)));
      }
      #pragma unroll
      for (int ms = 0; ms < 4; ++ms)
        #pragma unroll
        for (int ns = 0; ns < 4; ++ns)
          acc[ms][ns] = __builtin_amdgcn_mfma_f32_16x16x32_bf16(
              af[ms], bfr[ns], acc[ms][ns], 0, 0, 0);
    }
    __builtin_amdgcn_s_setprio(0);
  }

  const int ob = o0 + oh;  // wave-uniform output-channel base
  __syncthreads();         // all waves done with T1/T2 before epilogue reuse
  if (EPI == 0) {
    const int tsr = ob >> 8;        // 0=q 1=k 2=v (block-uniform)
    const int h = (ob >> 6) & 3;
    if (tsr < 2) {
      // q scale folds 1/sqrt(64) AND log2(e) so softmax uses exp2 directly
      const float sc = (tsr == 0) ? 0.18033688f : 1.0f;
      ushort* dst = (tsr == 0 ? qT : kT) + ((size_t)(b * 4 + h)) * NS * ND;
      // per-wave LDS transpose tile [64 s][64 d] in T1/T2 (w*8192)
      char* ep = smem + w * 8192;
      #pragma unroll
      for (int ms = 0; ms < 4; ++ms) {
        const float4 bv = *(const float4*)(bias + ob + ms * 16 + g * 4);
        const int d2 = (ms * 16 + g * 4) * 2;  // byte offset of d0
        #pragma unroll
        for (int ns = 0; ns < 4; ++ns) {
          const int sr = ns * 16 + li;
          ushort4 pk;
          pk.x = f2bf((acc[ms][ns][0] + bv.x) * sc);
          pk.y = f2bf((acc[ms][ns][1] + bv.y) * sc);
          pk.z = f2bf((acc[ms][ns][2] + bv.z) * sc);
          pk.w = f2bf((acc[ms][ns][3] + bv.w) * sc);
          *(ushort4*)(ep + sr * 128 + (d2 ^ ((sr & 7) << 4))) = pk;
        }
      }
      // read back rows -> fully coalesced 16B global stores
      #pragma unroll
      for (int i = 0; i < 8; ++i) {
        const int idx = l + 64 * i;          // 512 chunks per wave
        const int sr = idx >> 3, c8 = idx & 7;
        short8 v = *(const short8*)(ep + sr * 128 + ((c8 * 16) ^ ((sr & 7) << 4)));
        *(short8*)(dst + (size_t)(s0 + sh + sr) * ND + c8 * 8) = v;
      }
    } else {
      ushort* dst = vN + ((size_t)(b * 4 + h)) * ND * NS;
      #pragma unroll
      for (int ms = 0; ms < 4; ++ms) {
        const float4 bv = *(const float4*)(bias + ob + ms * 16 + g * 4);
        const float bvr[4] = {bv.x, bv.y, bv.z, bv.w};
        #pragma unroll
        for (int r = 0; r < 4; ++r) {
          const int d = ms * 16 + g * 4 + r;
          #pragma unroll
          for (int ns = 0; ns < 4; ++ns) {
            const int s = s0 + sh + ns * 16 + li;
            dst[(size_t)d * NS + s] = f2bf(acc[ms][ns][r] + bvr[r]);
          }
        }
      }
    }
  } else {
    float* outb = OUT + (size_t)b * NC * NS;
    const float* xb = X + (size_t)b * NC * NS;
    #pragma unroll
    for (int ms = 0; ms < 4; ++ms) {
      const float4 bv = *(const float4*)(bias + ob + ms * 16 + g * 4);
      const float bvr[4] = {bv.x, bv.y, bv.z, bv.w};
      #pragma unroll
      for (int r = 0; r < 4; ++r) {
        const int c = ob + ms * 16 + g * 4 + r;
        #pragma unroll
        for (int ns = 0; ns < 4; ++ns) {
          const int s = s0 + sh + ns * 16 + li;
          const size_t a = (size_t)c * NS + s;
          outb[a] = acc[ms][ns][r] + bvr[r] + xb[a];
        }
      }
    }
  }
}

// ---------------------------------------------------------------------------
// Kernel 3: MFMA flash attention v5 + transpose epilogue (coalesced att2).
// ---------------------------------------------------------------------------
__global__ __launch_bounds__(512, 2) void attn_kernel(
    const ushort* __restrict__ qT, const ushort* __restrict__ kT,
    const ushort* __restrict__ vN, ushort* __restrict__ att2) {
  __shared__ char smem[65536];
  const int o_id = blockIdx.x;                 // 256 blocks
  const int wg = (o_id & 7) * 32 + (o_id >> 3);
  const int b = wg >> 4, h = (wg >> 2) & 3;
  const int sq0 = (wg & 3) * 256;
  const int t = threadIdx.x, w = t >> 6, l = t & 63;
  const int g = l >> 4, li = l & 15;
  const int sw = (li & 7) << 4;
  char* Ps = smem + 32768 + w * 4096;  // per-wave [32 q][64 k] bf16, swizzled
  const size_t bh = (size_t)(b * 4 + h);
  const ushort* qbase = qT + bh * NS * ND + (size_t)sq0 * ND;
  const ushort* kbase = kT + bh * NS * ND;
  const ushort* vbase = vN + bh * ND * NS;

  // ---- stage Q (256 rows x 64 d) into [32K,64K), hoist B-fragments ----
  #pragma unroll
  for (int i = 0; i < 4; ++i) {
    const int f = t + 512 * i;       // 0..2047 short8 chunks
    const int row = f >> 3, c8 = f & 7;
    short8 v = *(const short8*)(qbase + (size_t)row * ND + c8 * 8);
    *(short8*)(smem + 32768 + ((row * 128 + c8 * 16) ^ ((row & 7) << 4))) = v;
  }
  __syncthreads();
  short8 aq[2][2];
  #pragma unroll
  for (int m = 0; m < 2; ++m) {
    const int row = w * 32 + m * 16 + li;   // row&7 == li&7
    aq[m][0] = *(const short8*)(smem + 32768 + row * 128 + ((g * 16) ^ sw));
    aq[m][1] = *(const short8*)(smem + 32768 + row * 128 + ((64 + g * 16) ^ sw));
  }

  // ---- prologue: stage K/V tile 0 into buf0 (1 chunk each per thread) ----
  const int srow = t >> 3, sc8 = t & 7;   // 64 rows x 8 chunks = 512 threads
  const int sdst = srow * 128 + ((sc8 * 16) ^ ((srow & 7) << 4));
  {
    short8 k0 = *(const short8*)(kbase + (size_t)srow * ND + sc8 * 8);
    short8 v0 = *(const short8*)(vbase + (size_t)srow * NS + sc8 * 8);
    *(short8*)(smem + sdst) = k0;
    *(short8*)(smem + 8192 + sdst) = v0;
  }

  f32x4 acc[2][4];
  #pragma unroll
  for (int m = 0; m < 2; ++m)
    #pragma unroll
    for (int dt = 0; dt < 4; ++dt) acc[m][dt] = (f32x4){0.f, 0.f, 0.f, 0.f};
  float lsum[2] = {0.f, 0.f};

  for (int kt = 0; kt < 16; ++kt) {
    __syncthreads();   // buf[kt&1] staged; previous tile's reads complete
    char* Kc = smem + (kt & 1) * 16384;
    char* Vc = Kc + 8192;

    // issue next tile's global loads (latency hidden under compute)
    short8 nk, nv;
    if (kt < 15) {
      nk = *(const short8*)(kbase + (size_t)(kt + 1) * 64 * ND +
                            (size_t)srow * ND + sc8 * 8);
      nv = *(const short8*)(vbase + (size_t)srow * NS + (kt + 1) * 64 + sc8 * 8);
    }

    // ---- swapped QK^T + softmax, per 16-key subtile x 2 q-halves ----
    __builtin_amdgcn_s_setprio(1);
    #pragma unroll
    for (int kst = 0; kst < 4; ++kst) {
      const int krow = kst * 16 + li;
      const short8 bk0 = *(const short8*)(Kc + krow * 128 + ((g * 16) ^ sw));
      const short8 bk1 = *(const short8*)(Kc + krow * 128 + ((64 + g * 16) ^ sw));
      #pragma unroll
      for (int m = 0; m < 2; ++m) {
        f32x4 sT = {0.f, 0.f, 0.f, 0.f};
        sT = __builtin_amdgcn_mfma_f32_16x16x32_bf16(bk0, aq[m][0], sT, 0, 0, 0);
        sT = __builtin_amdgcn_mfma_f32_16x16x32_bf16(bk1, aq[m][1], sT, 0, 0, 0);
        // lane holds S[q = sq0+w*32+m*16+li][key = kt*64+kst*16+4g+r]
        const float p0 = __builtin_amdgcn_exp2f(sT[0]);
        const float p1 = __builtin_amdgcn_exp2f(sT[1]);
        const float p2 = __builtin_amdgcn_exp2f(sT[2]);
        const float p3 = __builtin_amdgcn_exp2f(sT[3]);
        lsum[m] += (p0 + p1) + (p2 + p3);
        uint2 pk;
        pk.x = cvt_pk_bf16(p0, p1);
        pk.y = cvt_pk_bf16(p2, p3);
        *(uint2*)(Ps + (m * 16 + li) * 128 + ((kst * 32 + 8 * g) ^ sw)) = pk;
      }
    }
    __builtin_amdgcn_s_setprio(0);

    // ---- PV: acc[m][dt] += P[32q x 64k] * V[64k x 64d] ----
    __builtin_amdgcn_s_setprio(1);
    #pragma unroll
    for (int ks2 = 0; ks2 < 2; ++ks2) {
      short8 pa[2];
      #pragma unroll
      for (int m = 0; m < 2; ++m)
        pa[m] = *(const short8*)(Ps + (m * 16 + li) * 128 +
                                 ((ks2 * 64 + g * 16) ^ sw));
      #pragma unroll
      for (int dt = 0; dt < 4; ++dt) {
        const int vrow = dt * 16 + li;
        const short8 bv = *(const short8*)(Vc + vrow * 128 +
                                           ((ks2 * 64 + g * 16) ^ sw));
        #pragma unroll
        for (int m = 0; m < 2; ++m)
          acc[m][dt] = __builtin_amdgcn_mfma_f32_16x16x32_bf16(
              pa[m], bv, acc[m][dt], 0, 0, 0);
      }
    }
    __builtin_amdgcn_s_setprio(0);

    // ---- write next tile to the other buffer ----
    if (kt < 15) {
      char* Kn = smem + ((kt + 1) & 1) * 16384;
      *(short8*)(Kn + sdst) = nk;
      *(short8*)(Kn + 8192 + sdst) = nv;
    }
  }

  // ---- final l reduction (4 g-lanes share each q) and redistribution ----
  float lr[2][4];
  #pragma unroll
  for (int m = 0; m < 2; ++m) {
    float s = lsum[m];
    s += __shfl_xor(s, 16, 64);
    s += __shfl_xor(s, 32, 64);     // all lanes: l[q = w*32 + m*16 + li]
    const float linv = 1.f / s;
    #pragma unroll
    for (int r = 0; r < 4; ++r) lr[m][r] = __shfl(linv, g * 4 + r, 64);
  }

  // ---- transpose epilogue via per-wave Ps tile [32 q][64 d] ----
  #pragma unroll
  for (int m = 0; m < 2; ++m)
    #pragma unroll
    for (int dt = 0; dt < 4; ++dt)
      #pragma unroll
      for (int r = 0; r < 4; ++r) {
        const int q = m * 16 + g * 4 + r;
        *(ushort*)(Ps + q * 128 + (((dt * 16 + li) * 2) ^ ((q & 7) << 4))) =
            f2bf(acc[m][dt][r] * lr[m][r]);
      }
  ushort* ob2 = att2 + ((size_t)b * NS + sq0 + w * 32) * NC + h * 64;
  #pragma unroll
  for (int i = 0; i < 4; ++i) {
    const int idx = l + 64 * i;     // 256 chunks per wave
    const int q = idx >> 3, c8 = idx & 7;
    short8 v = *(const short8*)(Ps + q * 128 + ((c8 * 16) ^ ((q & 7) << 4)));
    *(short8*)(ob2 + (size_t)q * NC + c8 * 8) = v;
  }
}

// ---------------------------------------------------------------------------
// ws (ushort): xT[4.19M] qT[4.19M] kT[4.19M] vN[4.19M] att2[4.19M]
//              wbf[262144] | partials f2[1024]
// ---------------------------------------------------------------------------
extern "C" void kernel_launch(void* const* d_in, const int* in_sizes, int n_in,
                              void* d_out, int out_size, void* d_ws, size_t ws_size,
                              hipStream_t stream) {
  const float* x      = (const float*)d_in[0];
  const float* norm_w = (const float*)d_in[1];
  const float* norm_b = (const float*)d_in[2];
  const float* qkv_w  = (const float*)d_in[3];
  const float* qkv_b  = (const float*)d_in[4];
  const float* proj_w = (const float*)d_in[5];
  const float* proj_b = (const float*)d_in[6];
  float* out = (float*)d_out;

  ushort* xT   = (ushort*)d_ws;
  ushort* qT   = xT + (size_t)4194304;
  ushort* kT   = qT + (size_t)4194304;
  ushort* vN   = kT + (size_t)4194304;
  ushort* att2 = vN + (size_t)4194304;
  ushort* wbf  = att2 + (size_t)4194304;
  float2* partials = (float2*)(wbf + (size_t)262144);
  ushort* wq = wbf;
  ushort* wp = wbf + (size_t)196608;

  gnstatT_wconv_kernel<<<dim3(1280), 256, 0, stream>>>(
      x, xT, partials, qkv_w, proj_w, wbf);
  mfma_gemm_kernel<0, 6><<<dim3(768), 256, 0, stream>>>(
      wq, qkv_b, xT, nullptr, norm_w, norm_b, partials, qT, kT, vN, nullptr);
  attn_kernel<<<dim3(256), 512, 0, stream>>>(qT, kT, vN, att2);
  mfma_gemm_kernel<1, 2><<<dim3(256), 256, 0, stream>>>(
      wp, proj_b, att2, x, nullptr, nullptr, nullptr, nullptr, nullptr, nullptr, out);
}

// Round 14
// 58.466 us; speedup vs baseline: 1.0093x; 1.0093x over previous
//
#include <hip/hip_runtime.h>

// AttentionBlock: B=16, C=256, H=W=32, NH=4, GROUPS=8
#define NB 16
#define NC 256
#define NS 1024   // H*W
#define NNH 4
#define ND 64     // C/NH
#define GN_EPS 1e-5f

typedef __attribute__((ext_vector_type(8))) short short8;   // 8 bf16 (4 VGPRs)
typedef __attribute__((ext_vector_type(4))) float f32x4;    // MFMA C/D

static __device__ __forceinline__ ushort f2bf(float x) {
  union { float f; unsigned u; } c; c.f = x;
  unsigned r = (c.u + 0x7fffu + ((c.u >> 16) & 1u)) >> 16;  // RNE
  return (ushort)r;
}
static __device__ __forceinline__ unsigned cvt_pk_bf16(float lo, float hi) {
  unsigned r;
  asm("v_cvt_pk_bf16_f32 %0, %1, %2" : "=v"(r) : "v"(lo), "v"(hi));
  return r;  // low16 = bf16(lo), high16 = bf16(hi)
}

// ---------------------------------------------------------------------------
// Kernel 1: blocks 0..1023: x [b][c][s] fp32 -> xT [b][s][c] RAW bf16 (LDS
// transpose) + per-(b,g,s-tile) stat partials.  Blocks 1024..1279: weight
// fp32->bf16 convert (qkv_w then proj_w).
// ---------------------------------------------------------------------------
__global__ __launch_bounds__(256) void gnstatT_wconv_kernel(
    const float* __restrict__ x, ushort* __restrict__ xT,
    float2* __restrict__ partials, const float* __restrict__ qw,
    const float* __restrict__ pw, ushort* __restrict__ wbf) {
  const int bid = blockIdx.x;
  const int t = threadIdx.x;
  if (bid >= 1024) {  // ---- weight convert: 65536 float4s over 256 blocks ----
    const int i = (bid - 1024) * 256 + t;
    const float4 v = (i < 49152) ? *(const float4*)(qw + (size_t)i * 4)
                                 : *(const float4*)(pw + (size_t)(i - 49152) * 4);
    ushort4 u;
    u.x = f2bf(v.x); u.y = f2bf(v.y); u.z = f2bf(v.z); u.w = f2bf(v.w);
    *(ushort4*)(wbf + (size_t)i * 4) = u;
    return;
  }
  const int bg = bid >> 3, st = bid & 7;
  const int b = bg >> 3, gg = bg & 7;

  __shared__ ushort tile[128][36];  // 72B rows
  __shared__ float rs1[4], rs2[4];
  const int s4 = (t & 31) * 4;
  float s1 = 0.f, s2 = 0.f;
  #pragma unroll
  for (int i = 0; i < 4; ++i) {
    const int c = (t >> 5) + 8 * i;
    const int cg = gg * 32 + c;
    const float4 v = *(const float4*)(x + ((size_t)(b * NC + cg)) * NS +
                                      st * 128 + s4);
    s1 += v.x + v.y + v.z + v.w;
    s2 += v.x * v.x + v.y * v.y + v.z * v.z + v.w * v.w;
    tile[s4 + 0][c] = f2bf(v.x);
    tile[s4 + 1][c] = f2bf(v.y);
    tile[s4 + 2][c] = f2bf(v.z);
    tile[s4 + 3][c] = f2bf(v.w);
  }
  #pragma unroll
  for (int o = 32; o > 0; o >>= 1) {
    s1 += __shfl_down(s1, o, 64);
    s2 += __shfl_down(s2, o, 64);
  }
  if ((t & 63) == 0) { rs1[t >> 6] = s1; rs2[t >> 6] = s2; }
  __syncthreads();   // orders tile writes AND rs writes
  if (t == 0)
    partials[bid] = make_float2(rs1[0] + rs1[1] + rs1[2] + rs1[3],
                                rs2[0] + rs2[1] + rs2[2] + rs2[3]);
  #pragma unroll
  for (int i = 0; i < 4; ++i) {
    const int idx = t + 256 * i;         // 128 rows x 8 chunks
    const int sr = idx >> 3, ch4 = (idx & 7) * 4;
    const ushort4 u = *(const ushort4*)&tile[sr][ch4];
    *(ushort4*)(xT + ((size_t)(b * NS + st * 128 + sr)) * NC + gg * 32 + ch4) = u;
  }
}

// ---------------------------------------------------------------------------
// Kernel 2/4: bf16 MFMA GEMM, XCD-chunked 1D grid, T14 async-stage K-loop.
// EPI=0: DATA = raw xT; per-channel GN affine (from partials+nw/nb, built in
//        LDS) applied at ds_write time ("cooking"); qkv repack epilogue.
// EPI=1: DATA = att2 raw; proj epilogue fp32 + bias + residual.
// ---------------------------------------------------------------------------
template <int EPI, int YDIM>
__global__ __launch_bounds__(256) void mfma_gemm_kernel(
    const ushort* __restrict__ Wbf, const float* __restrict__ bias,
    const ushort* __restrict__ DATA, const float* __restrict__ X,
    const float* __restrict__ nw, const float* __restrict__ nb,
    const float2* __restrict__ partials,
    ushort* __restrict__ qT, ushort* __restrict__ kT, ushort* __restrict__ vN,
    float* __restrict__ OUT) {
  __shared__ char smem[32768];
  __shared__ float2 sm_wb[256];  // per-channel {wgt, bia} (EPI=0)
  __shared__ float2 sm_g[8];
  char* T1 = smem;          // W-tile   [128 o][64 c] bf16, swizzled 128B rows
  char* T2 = smem + 16384;  // data-tile[128 s][64 c] bf16, swizzled
  const int nwg = 8 * YDIM * NB;
  const int o_id = blockIdx.x;
  const int wg = (o_id & 7) * (nwg >> 3) + (o_id >> 3);
  const int b = wg / (8 * YDIM);
  const int o0 = ((wg >> 3) % YDIM) * 128, s0 = (wg & 7) * 128;
  const int t = threadIdx.x, w = t >> 6, l = t & 63;
  const int g = l >> 4, li = l & 15;
  const ushort* wrow = Wbf + (size_t)o0 * NC;
  const ushort* drow = DATA + ((size_t)b * NS + s0) * NC;

  const int oh = (w >> 1) * 64, sh = (w & 1) * 64;  // wave quadrant
  const int srow = t >> 3, sce = (t & 7) * 8;       // staging row/col (elems)
  // rows srow+32*i share (row&7) == (srow&7) -> same swizzle term for all i
  const int sds = srow * 128 + (((t & 7) * 16) ^ ((srow & 7) << 4));

  short8 r1[4], r2[4];   // staged regs: rows srow+32*i of current K-tile
  #pragma unroll
  for (int i = 0; i < 4; ++i) {
    r1[i] = *(const short8*)(wrow + (size_t)(srow + 32 * i) * NC + sce);
    r2[i] = *(const short8*)(drow + (size_t)(srow + 32 * i) * NC + sce);
  }

  if (EPI == 0) {  // build per-channel GN affine table in LDS
    if (t < 8) {
      float s1 = 0.f, s2 = 0.f;
      #pragma unroll
      for (int j = 0; j < 8; ++j) {
        const float2 p = partials[(b * 8 + t) * 8 + j];
        s1 += p.x; s2 += p.y;
      }
      const float mean = s1 * (1.f / 32768.f);
      const float var = s2 * (1.f / 32768.f) - mean * mean;
      sm_g[t] = make_float2(mean, rsqrtf(var + GN_EPS));
    }
    __syncthreads();
    const float2 ms = sm_g[t >> 5];
    const float wgt = nw[t] * ms.y;
    sm_wb[t] = make_float2(wgt, nb[t] - ms.x * wgt);
    // (first K-loop barrier orders sm_wb writes before first cook read)
  }

  f32x4 acc[4][4];
  #pragma unroll
  for (int i = 0; i < 4; ++i)
    #pragma unroll
    for (int j = 0; j < 4; ++j) acc[i][j] = (f32x4){0.f, 0.f, 0.f, 0.f};

  for (int k0 = 0; k0 < NC; k0 += 64) {
    __syncthreads();   // previous iteration's LDS reads complete
    #pragma unroll
    for (int i = 0; i < 4; ++i)
      *(short8*)(T1 + sds + i * 4096) = r1[i];
    if (EPI == 0) {  // cook: y = bf16(x)*wgt + bia, per channel k0+sce+j
      float2 wb[8];
      #pragma unroll
      for (int j = 0; j < 8; ++j) wb[j] = sm_wb[k0 + sce + j];
      #pragma unroll
      for (int i = 0; i < 4; ++i) {
        union { short8 s; unsigned u[4]; } a, o;
        a.s = r2[i];
        #pragma unroll
        for (int j = 0; j < 4; ++j) {
          const float lo = __uint_as_float(a.u[j] << 16);
          const float hi = __uint_as_float(a.u[j] & 0xffff0000u);
          o.u[j] = cvt_pk_bf16(fmaf(lo, wb[2 * j].x, wb[2 * j].y),
                               fmaf(hi, wb[2 * j + 1].x, wb[2 * j + 1].y));
        }
        *(short8*)(T2 + sds + i * 4096) = o.s;
      }
    } else {
      #pragma unroll
      for (int i = 0; i < 4; ++i)
        *(short8*)(T2 + sds + i * 4096) = r2[i];
    }
    __syncthreads();
    if (k0 + 64 < NC) {  // issue next tile's loads; hide under MFMA
      #pragma unroll
      for (int i = 0; i < 4; ++i) {
        r1[i] = *(const short8*)(wrow + (size_t)(srow + 32 * i) * NC + k0 + 64 + sce);
        r2[i] = *(const short8*)(drow + (size_t)(srow + 32 * i) * NC + k0 + 64 + sce);
      }
    }
    __builtin_amdgcn_s_setprio(1);
    #pragma unroll
    for (int kk = 0; kk < 2; ++kk) {
      short8 af[4], bfr[4];
      #pragma unroll
      for (int ms = 0; ms < 4; ++ms) {
        const int row = oh + ms * 16 + li;
        af[ms] = *(const short8*)(T1 + row * 128 +
                                  ((kk * 64 + g * 16) ^ ((row & 7) << 4)));
      }
      #pragma unroll
      for (int ns = 0; ns < 4; ++ns) {
        const int row = sh + ns * 16 + li;
        bfr[ns] = *(const short8*)(T2 + row * 128 +
                                   ((kk * 64 + g * 16) ^ ((row & 7) << 4)));
      }
      #pragma unroll
      for (int ms = 0; ms < 4; ++ms)
        #pragma unroll
        for (int ns = 0; ns < 4; ++ns)
          acc[ms][ns] = __builtin_amdgcn_mfma_f32_16x16x32_bf16(
              af[ms], bfr[ns], acc[ms][ns], 0, 0, 0);
    }
    __builtin_amdgcn_s_setprio(0);
  }

  const int ob = o0 + oh;  // wave-uniform output-channel base
  if (EPI == 0) {
    const int tsr = ob >> 8;        // 0=q 1=k 2=v
    const int h = (ob >> 6) & 3;
    if (tsr < 2) {
      // q scale folds 1/sqrt(64) AND log2(e) so softmax uses exp2 directly
      const float sc = (tsr == 0) ? 0.18033688f : 1.0f;
      ushort* dst = (tsr == 0 ? qT : kT) + ((size_t)(b * 4 + h)) * NS * ND;
      #pragma unroll
      for (int ms = 0; ms < 4; ++ms) {
        const float4 bv = *(const float4*)(bias + ob + ms * 16 + g * 4);
        const int d0 = ms * 16 + g * 4;
        #pragma unroll
        for (int ns = 0; ns < 4; ++ns) {
          const int s = s0 + sh + ns * 16 + li;
          ushort4 pk;
          pk.x = f2bf((acc[ms][ns][0] + bv.x) * sc);
          pk.y = f2bf((acc[ms][ns][1] + bv.y) * sc);
          pk.z = f2bf((acc[ms][ns][2] + bv.z) * sc);
          pk.w = f2bf((acc[ms][ns][3] + bv.w) * sc);
          *(ushort4*)(dst + (size_t)s * ND + d0) = pk;
        }
      }
    } else {
      ushort* dst = vN + ((size_t)(b * 4 + h)) * ND * NS;
      #pragma unroll
      for (int ms = 0; ms < 4; ++ms) {
        const float4 bv = *(const float4*)(bias + ob + ms * 16 + g * 4);
        const float bvr[4] = {bv.x, bv.y, bv.z, bv.w};
        #pragma unroll
        for (int r = 0; r < 4; ++r) {
          const int d = ms * 16 + g * 4 + r;
          #pragma unroll
          for (int ns = 0; ns < 4; ++ns) {
            const int s = s0 + sh + ns * 16 + li;
            dst[(size_t)d * NS + s] = f2bf(acc[ms][ns][r] + bvr[r]);
          }
        }
      }
    }
  } else {
    float* outb = OUT + (size_t)b * NC * NS;
    const float* xb = X + (size_t)b * NC * NS;
    #pragma unroll
    for (int ms = 0; ms < 4; ++ms) {
      const float4 bv = *(const float4*)(bias + ob + ms * 16 + g * 4);
      const float bvr[4] = {bv.x, bv.y, bv.z, bv.w};
      #pragma unroll
      for (int r = 0; r < 4; ++r) {
        const int c = ob + ms * 16 + g * 4 + r;
        #pragma unroll
        for (int ns = 0; ns < 4; ++ns) {
          const int s = s0 + sh + ns * 16 + li;
          const size_t a = (size_t)c * NS + s;
          outb[a] = acc[ms][ns][r] + bvr[r] + xb[a];
        }
      }
    }
  }
}

// ---------------------------------------------------------------------------
// Kernel 3: MFMA flash attention v5 (identical to R6/R10/R11).
// ---------------------------------------------------------------------------
__global__ __launch_bounds__(512, 2) void attn_kernel(
    const ushort* __restrict__ qT, const ushort* __restrict__ kT,
    const ushort* __restrict__ vN, ushort* __restrict__ att2) {
  __shared__ char smem[65536];
  const int o_id = blockIdx.x;                 // 256 blocks
  const int wg = (o_id & 7) * 32 + (o_id >> 3);
  const int b = wg >> 4, h = (wg >> 2) & 3;
  const int sq0 = (wg & 3) * 256;
  const int t = threadIdx.x, w = t >> 6, l = t & 63;
  const int g = l >> 4, li = l & 15;
  const int sw = (li & 7) << 4;
  char* Ps = smem + 32768 + w * 4096;  // per-wave [32 q][64 k] bf16, swizzled
  const size_t bh = (size_t)(b * 4 + h);
  const ushort* qbase = qT + bh * NS * ND + (size_t)sq0 * ND;
  const ushort* kbase = kT + bh * NS * ND;
  const ushort* vbase = vN + bh * ND * NS;

  // ---- stage Q (256 rows x 64 d) into [32K,64K), hoist B-fragments ----
  #pragma unroll
  for (int i = 0; i < 4; ++i) {
    const int f = t + 512 * i;       // 0..2047 short8 chunks
    const int row = f >> 3, c8 = f & 7;
    short8 v = *(const short8*)(qbase + (size_t)row * ND + c8 * 8);
    *(short8*)(smem + 32768 + ((row * 128 + c8 * 16) ^ ((row & 7) << 4))) = v;
  }
  __syncthreads();
  short8 aq[2][2];
  #pragma unroll
  for (int m = 0; m < 2; ++m) {
    const int row = w * 32 + m * 16 + li;   // row&7 == li&7
    aq[m][0] = *(const short8*)(smem + 32768 + row * 128 + ((g * 16) ^ sw));
    aq[m][1] = *(const short8*)(smem + 32768 + row * 128 + ((64 + g * 16) ^ sw));
  }

  // ---- prologue: stage K/V tile 0 into buf0 (1 chunk each per thread) ----
  const int srow = t >> 3, sc8 = t & 7;   // 64 rows x 8 chunks = 512 threads
  const int sdst = srow * 128 + ((sc8 * 16) ^ ((srow & 7) << 4));
  {
    short8 k0 = *(const short8*)(kbase + (size_t)srow * ND + sc8 * 8);
    short8 v0 = *(const short8*)(vbase + (size_t)srow * NS + sc8 * 8);
    *(short8*)(smem + sdst) = k0;
    *(short8*)(smem + 8192 + sdst) = v0;
  }

  f32x4 acc[2][4];
  #pragma unroll
  for (int m = 0; m < 2; ++m)
    #pragma unroll
    for (int dt = 0; dt < 4; ++dt) acc[m][dt] = (f32x4){0.f, 0.f, 0.f, 0.f};
  float lsum[2] = {0.f, 0.f};

  for (int kt = 0; kt < 16; ++kt) {
    __syncthreads();   // buf[kt&1] staged; previous tile's reads complete
    char* Kc = smem + (kt & 1) * 16384;
    char* Vc = Kc + 8192;

    // issue next tile's global loads (latency hidden under compute)
    short8 nk, nv;
    if (kt < 15) {
      nk = *(const short8*)(kbase + (size_t)(kt + 1) * 64 * ND +
                            (size_t)srow * ND + sc8 * 8);
      nv = *(const short8*)(vbase + (size_t)srow * NS + (kt + 1) * 64 + sc8 * 8);
    }

    // ---- swapped QK^T + softmax, per 16-key subtile x 2 q-halves ----
    __builtin_amdgcn_s_setprio(1);
    #pragma unroll
    for (int kst = 0; kst < 4; ++kst) {
      const int krow = kst * 16 + li;
      const short8 bk0 = *(const short8*)(Kc + krow * 128 + ((g * 16) ^ sw));
      const short8 bk1 = *(const short8*)(Kc + krow * 128 + ((64 + g * 16) ^ sw));
      #pragma unroll
      for (int m = 0; m < 2; ++m) {
        f32x4 sT = {0.f, 0.f, 0.f, 0.f};
        sT = __builtin_amdgcn_mfma_f32_16x16x32_bf16(bk0, aq[m][0], sT, 0, 0, 0);
        sT = __builtin_amdgcn_mfma_f32_16x16x32_bf16(bk1, aq[m][1], sT, 0, 0, 0);
        // lane holds S[q = sq0+w*32+m*16+li][key = kt*64+kst*16+4g+r]
        const float p0 = __builtin_amdgcn_exp2f(sT[0]);
        const float p1 = __builtin_amdgcn_exp2f(sT[1]);
        const float p2 = __builtin_amdgcn_exp2f(sT[2]);
        const float p3 = __builtin_amdgcn_exp2f(sT[3]);
        lsum[m] += (p0 + p1) + (p2 + p3);
        uint2 pk;
        pk.x = cvt_pk_bf16(p0, p1);
        pk.y = cvt_pk_bf16(p2, p3);
        *(uint2*)(Ps + (m * 16 + li) * 128 + ((kst * 32 + 8 * g) ^ sw)) = pk;
      }
    }
    __builtin_amdgcn_s_setprio(0);

    // ---- PV: acc[m][dt] += P[32q x 64k] * V[64k x 64d] ----
    __builtin_amdgcn_s_setprio(1);
    #pragma unroll
    for (int ks2 = 0; ks2 < 2; ++ks2) {
      short8 pa[2];
      #pragma unroll
      for (int m = 0; m < 2; ++m)
        pa[m] = *(const short8*)(Ps + (m * 16 + li) * 128 +
                                 ((ks2 * 64 + g * 16) ^ sw));
      #pragma unroll
      for (int dt = 0; dt < 4; ++dt) {
        const int vrow = dt * 16 + li;
        const short8 bv = *(const short8*)(Vc + vrow * 128 +
                                           ((ks2 * 64 + g * 16) ^ sw));
        #pragma unroll
        for (int m = 0; m < 2; ++m)
          acc[m][dt] = __builtin_amdgcn_mfma_f32_16x16x32_bf16(
              pa[m], bv, acc[m][dt], 0, 0, 0);
      }
    }
    __builtin_amdgcn_s_setprio(0);

    // ---- write next tile to the other buffer ----
    if (kt < 15) {
      char* Kn = smem + ((kt + 1) & 1) * 16384;
      *(short8*)(Kn + sdst) = nk;
      *(short8*)(Kn + 8192 + sdst) = nv;
    }
  }

  // ---- final l reduction (4 g-lanes share each q) and redistribution ----
  float lr[2][4];
  #pragma unroll
  for (int m = 0; m < 2; ++m) {
    float s = lsum[m];
    s += __shfl_xor(s, 16, 64);
    s += __shfl_xor(s, 32, 64);     // all lanes: l[q = w*32 + m*16 + li]
    const float linv = 1.f / s;
    #pragma unroll
    for (int r = 0; r < 4; ++r) lr[m][r] = __shfl(linv, g * 4 + r, 64);
  }

  // epilogue: out[b][s][c], c = h*64 + dt*16 + li, s = sq0+w*32+m*16+g*4+r
  ushort* obase = att2 + ((size_t)b * NS + sq0 + w * 32) * NC + h * 64;
  #pragma unroll
  for (int m = 0; m < 2; ++m)
    #pragma unroll
    for (int dt = 0; dt < 4; ++dt)
      #pragma unroll
      for (int r = 0; r < 4; ++r)
        obase[(size_t)(m * 16 + g * 4 + r) * NC + dt * 16 + li] =
            f2bf(acc[m][dt][r] * lr[m][r]);
}

// ---------------------------------------------------------------------------
// ws (ushort): xT[4.19M] qT[4.19M] kT[4.19M] vN[4.19M] att2[4.19M]
//              wbf[262144] | partials f2[1024]
// ---------------------------------------------------------------------------
extern "C" void kernel_launch(void* const* d_in, const int* in_sizes, int n_in,
                              void* d_out, int out_size, void* d_ws, size_t ws_size,
                              hipStream_t stream) {
  const float* x      = (const float*)d_in[0];
  const float* norm_w = (const float*)d_in[1];
  const float* norm_b = (const float*)d_in[2];
  const float* qkv_w  = (const float*)d_in[3];
  const float* qkv_b  = (const float*)d_in[4];
  const float* proj_w = (const float*)d_in[5];
  const float* proj_b = (const float*)d_in[6];
  float* out = (float*)d_out;

  ushort* xT   = (ushort*)d_ws;
  ushort* qT   = xT + (size_t)4194304;
  ushort* kT   = qT + (size_t)4194304;
  ushort* vN   = kT + (size_t)4194304;
  ushort* att2 = vN + (size_t)4194304;
  ushort* wbf  = att2 + (size_t)4194304;
  float2* partials = (float2*)(wbf + (size_t)262144);
  ushort* wq = wbf;
  ushort* wp = wbf + (size_t)196608;

  gnstatT_wconv_kernel<<<dim3(1280), 256, 0, stream>>>(
      x, xT, partials, qkv_w, proj_w, wbf);
  mfma_gemm_kernel<0, 6><<<dim3(768), 256, 0, stream>>>(
      wq, qkv_b, xT, nullptr, norm_w, norm_b, partials, qT, kT, vN, nullptr);
  attn_kernel<<<dim3(256), 512, 0, stream>>>(qT, kT, vN, att2);
  mfma_gemm_kernel<1, 2><<<dim3(256), 256, 0, stream>>>(
      wp, proj_b, att2, x, nullptr, nullptr, nullptr, nullptr, nullptr, nullptr, out);
}